// Round 3
// baseline (722.699 us; speedup 1.0000x reference)
//
#include <hip/hip_runtime.h>
#include <math.h>

#define BATCH     8
#define SEQ       512
#define VOCAB     32000
#define PADCOLS   31488.0f        // V - S identical NEG_BIG columns
#define NEG_BIG   (-1000000000.0f)
#define NUM_ITERS 20

// ---------------------------------------------------------------------------
// Kernel 1: ce[row] = logsumexp_V(pred[row,:]) - pred[row, tgt[row]]
// ONE WAVE per row (4096 waves = 1024 blocks x 256 thr).
//   - constant trip count (125) -> compiler unrolls, multiple loads in flight
//   - grouped online-LSE: local max of 4 comps, one rescale -> 5 exp / 4 elem
//   - two alternating accumulator pairs break the serial FMA chain
//   - no __syncthreads, no LDS; wave-only butterfly combine
// ---------------------------------------------------------------------------
__global__ __launch_bounds__(256) void ce_kernel(const float* __restrict__ pred,
                                                 const int*   __restrict__ tgt,
                                                 float*       __restrict__ ce) {
    const int tid  = threadIdx.x;
    const int lane = tid & 63;
    const int row  = (blockIdx.x << 2) + (tid >> 6);   // 4 waves/block, 1 row/wave
    const float4* __restrict__ p4 = (const float4*)(pred + (size_t)row * VOCAB);

    float m0 = -INFINITY, s0 = 0.0f;
    float m1 = -INFINITY, s1 = 0.0f;

    #pragma unroll 5
    for (int k = 0; k < 125; ++k) {                    // 8000 float4 / 64 lanes
        float4 v = p4[lane + (k << 6)];
        float lm = fmaxf(fmaxf(v.x, v.y), fmaxf(v.z, v.w));
        if (k & 1) {                                   // compile-time under unroll
            float nm = fmaxf(m1, lm);
            s1 = s1 * __expf(m1 - nm)
               + ((__expf(v.x - nm) + __expf(v.y - nm))
                + (__expf(v.z - nm) + __expf(v.w - nm)));
            m1 = nm;
        } else {
            float nm = fmaxf(m0, lm);
            s0 = s0 * __expf(m0 - nm)
               + ((__expf(v.x - nm) + __expf(v.y - nm))
                + (__expf(v.z - nm) + __expf(v.w - nm)));
            m0 = nm;
        }
    }

    // merge the two accumulator pairs
    float m = fmaxf(m0, m1);
    float s = s0 * __expf(m0 - m) + s1 * __expf(m1 - m);

    // 64-lane butterfly reduce of (m, s)
    #pragma unroll
    for (int off = 1; off < 64; off <<= 1) {
        float mo = __shfl_xor(m, off);
        float so = __shfl_xor(s, off);
        float mn = fmaxf(m, mo);
        s = s * __expf(m - mn) + so * __expf(mo - mn);
        m = mn;
    }

    if (lane == 0) {
        float lse = m + logf(s);
        ce[row] = lse - pred[(size_t)row * VOCAB + tgt[row]];
    }
}

// ---------------------------------------------------------------------------
// Kernel 2 (UNCHANGED — passed with absmax 0.0): structurally-reduced
// Sinkhorn. cost[b,s,:] == { u[b,s] at col 0, r[b,s] at 31488 pad cols };
// both logsumexp axes preserve this 2-value structure exactly.
// One block of 512 threads; wave w == batch b; each lane owns 8 s-positions.
// ---------------------------------------------------------------------------
__global__ __launch_bounds__(512) void sinkhorn_kernel(const float* __restrict__ ce,
                                                       float*       __restrict__ out) {
    const int tid  = threadIdx.x;
    const int b    = tid >> 6;     // wave index == batch index
    const int lane = tid & 63;

    float u[8], r[8], c[8];
    #pragma unroll
    for (int j = 0; j < 8; ++j) {
        c[j] = ce[b * SEQ + j * 64 + lane];   // coalesced
        u[j] = -c[j];                          // cost col 0 = -ce / TAU, TAU=1
        r[j] = NEG_BIG;                        // pad columns
    }

    for (int it = 0; it < NUM_ITERS; ++it) {
        // ---- axis-2 normalize (closed form over the 31489 columns) ----
        #pragma unroll
        for (int j = 0; j < 8; ++j) {
            float m   = fmaxf(u[j], r[j]);
            float sum = expf(u[j] - m) + PADCOLS * expf(r[j] - m);
            float L2  = m + logf(sum);
            u[j] -= L2;
            r[j] -= L2;
        }
        // ---- axis-1 normalize: lse over S=512 of u (wave-local, shfl only) ----
        {
            float m = u[0];
            #pragma unroll
            for (int j = 1; j < 8; ++j) m = fmaxf(m, u[j]);
            #pragma unroll
            for (int off = 1; off < 64; off <<= 1) m = fmaxf(m, __shfl_xor(m, off));
            float s = 0.0f;
            #pragma unroll
            for (int j = 0; j < 8; ++j) s += expf(u[j] - m);
            #pragma unroll
            for (int off = 1; off < 64; off <<= 1) s += __shfl_xor(s, off);
            float L1 = m + logf(s);
            #pragma unroll
            for (int j = 0; j < 8; ++j) u[j] -= L1;
        }
        // ---- same for r ----
        {
            float m = r[0];
            #pragma unroll
            for (int j = 1; j < 8; ++j) m = fmaxf(m, r[j]);
            #pragma unroll
            for (int off = 1; off < 64; off <<= 1) m = fmaxf(m, __shfl_xor(m, off));
            float s = 0.0f;
            #pragma unroll
            for (int j = 0; j < 8; ++j) s += expf(r[j] - m);
            #pragma unroll
            for (int off = 1; off < 64; off <<= 1) s += __shfl_xor(s, off);
            float L1 = m + logf(s);
            #pragma unroll
            for (int j = 0; j < 8; ++j) r[j] -= L1;
        }
    }

    // ---- loss_b = sum_s (exp(u) + 31488*exp(r)) * ce ----
    float acc = 0.0f;
    #pragma unroll
    for (int j = 0; j < 8; ++j)
        acc += (expf(u[j]) + PADCOLS * expf(r[j])) * c[j];
    #pragma unroll
    for (int off = 1; off < 64; off <<= 1) acc += __shfl_xor(acc, off);

    __shared__ float part[8];
    if (lane == 0) part[b] = acc;
    __syncthreads();
    if (tid == 0) {
        float t = 0.0f;
        #pragma unroll
        for (int w = 0; w < 8; ++w) t += part[w];
        out[0] = t / (float)BATCH;             // mean over batch
    }
}

// ---------------------------------------------------------------------------
extern "C" void kernel_launch(void* const* d_in, const int* in_sizes, int n_in,
                              void* d_out, int out_size, void* d_ws, size_t ws_size,
                              hipStream_t stream) {
    const float* pred = (const float*)d_in[0];   // (8,512,32000) f32
    const int*   tgt  = (const int*)d_in[1];     // (8,512) int
    float* out = (float*)d_out;                  // scalar f32
    float* ce  = (float*)d_ws;                   // 4096 f32 scratch

    ce_kernel<<<(BATCH * SEQ) / 4, 256, 0, stream>>>(pred, tgt, ce);
    sinkhorn_kernel<<<1, 512, 0, stream>>>(ce, out);
}